// Round 5
// baseline (1141.063 us; speedup 1.0000x reference)
//
#include <hip/hip_runtime.h>
#include <math.h>

typedef _Float16 half8 __attribute__((ext_vector_type(8)));
typedef float float4v __attribute__((ext_vector_type(4)));

#define SELU_ALPHA 1.6732632423543772f
#define SELU_SCALE 1.0507009873554805f

__device__ __forceinline__ float selu_f(float x) {
    return x > 0.f ? SELU_SCALE * x : SELU_SCALE * SELU_ALPHA * (__expf(x) - 1.f);
}
__device__ __forceinline__ float gate_f(float a, float sc, float sh) {
    // BN (pre-folded) -> SELU -> sigmoid
    float z = a * sc + sh;
    float s = selu_f(z);
    return 1.f / (1.f + __expf(-s));
}

// One-time prep:
//  - cast pw_w to f16 (layout [c4][cc], MFMA-B friendly)
//  - fold BN2 into scale/shift
//  - pack per-channel dw data: 9 weights + BN1 scale + BN1 shift + pad = 12 f
//  - zero the 256 row-pair progress flags
// threads: 32768 (wB) + 256 (bn2) + 1536 (dwpk) + 256 (flags) = 34816 = 136*256
__global__ __launch_bounds__(256) void prep_kernel(
    const float* __restrict__ pw_w,
    const float* __restrict__ g1, const float* __restrict__ b1,
    const float* __restrict__ m1, const float* __restrict__ v1,
    const float* __restrict__ g2, const float* __restrict__ b2,
    const float* __restrict__ m2, const float* __restrict__ v2,
    const float* __restrict__ dw_w,
    _Float16* __restrict__ wB, float* __restrict__ bn2, float* __restrict__ dwpk,
    int* __restrict__ flags)
{
    int i = blockIdx.x * 256 + threadIdx.x;
    if (i < 32768) {
        wB[i] = (_Float16)pw_w[i];
    } else if (i < 32768 + 256) {
        int c = i - 32768;
        float sc = g2[c] * rsqrtf(v2[c] + 1e-5f);
        bn2[c] = sc;
        bn2[256 + c] = b2[c] - m2[c] * sc;
    } else if (i < 32768 + 256 + 1536) {
        int j = i - 33024;
        int c = j / 12, k = j - c * 12;
        float val;
        if (k < 9) {
            val = dw_w[c * 9 + k];
        } else {
            float sc = g1[c] * rsqrtf(v1[c] + 1e-5f);
            if (k == 9) val = sc;
            else if (k == 10) val = b1[c] - m1[c] * sc;
            else val = 0.f;
        }
        dwpk[c * 12 + k] = val;
    } else if (i < 32768 + 256 + 1536 + 256) {
        flags[i - 34560] = 0;
    }
}

// Depthwise 3x3 + BN1 + SELU for 32 channels x one 64px row, into LDS A-tile.
// cc even; 3x3 factored into column sums P/Q/R so x-taps cost 2 shuffles.
__device__ __forceinline__ void dw_rows(
    const float* __restrict__ src0, const float* __restrict__ dwpk,
    int ccbase, int y0, int lane, _Float16* Alds)
{
    int p = (y0 << 6) + lane;
    #pragma unroll 4
    for (int it = 0; it < 16; ++it) {
        int cl = it << 1;                 // local channel 0,2,..,30
        int cc = ccbase + cl;             // global cc (even, wave-uniform)
        const float* chA = src0 + ((size_t)cl << 12);
        const float* chB = chA + 4096;
        float a0 = (y0 > 0)  ? chA[p - 64] : 0.f;
        float a1 = chA[p];
        float a2 = (y0 < 63) ? chA[p + 64] : 0.f;
        float c0 = (y0 > 0)  ? chB[p - 64] : 0.f;
        float c1 = chB[p];
        float c2 = (y0 < 63) ? chB[p + 64] : 0.f;
        const float4v* wp = (const float4v*)(dwpk + cc * 12);
        float4v wa0 = wp[0], wa1 = wp[1], wa2 = wp[2];   // ch A: w00..w22, sc, sh
        float4v wb0 = wp[3], wb1 = wp[4], wb2 = wp[5];   // ch B
        // column sums: P = kx0 taps, Q = kx1, R = kx2
        float P  = fmaf(wa0[0], a0, fmaf(wa0[3], a1, wa1[2] * a2));
        float Q  = fmaf(wa0[1], a0, fmaf(wa1[0], a1, wa1[3] * a2));
        float R  = fmaf(wa0[2], a0, fmaf(wa1[1], a1, wa2[0] * a2));
        float P2 = fmaf(wb0[0], c0, fmaf(wb0[3], c1, wb1[2] * c2));
        float Q2 = fmaf(wb0[1], c0, fmaf(wb1[0], c1, wb1[3] * c2));
        float R2 = fmaf(wb0[2], c0, fmaf(wb1[1], c1, wb2[0] * c2));
        float Pl  = __shfl_up(P, 1);    if (lane == 0)  Pl  = 0.f;
        float Rr  = __shfl_down(R, 1);  if (lane == 63) Rr  = 0.f;
        float P2l = __shfl_up(P2, 1);   if (lane == 0)  P2l = 0.f;
        float R2r = __shfl_down(R2, 1); if (lane == 63) R2r = 0.f;
        float za = fmaf(Pl + Q + Rr,    wa2[1], wa2[2]);
        float zb = fmaf(P2l + Q2 + R2r, wb2[1], wb2[2]);
        Alds[lane * 136 + cc]     = (_Float16)selu_f(za);
        Alds[lane * 136 + cc + 1] = (_Float16)selu_f(zb);
    }
}

// Persistent fused ConvLSTM, all 20 timesteps in one PLAIN launch.
// Block = one row-PAIR (rows 2y, 2y+1) of one batch; 512 threads = 8 waves
// (waves 0-3 -> row 2y, waves 4-7 -> row 2y+1; within each quad: waves 0,1
// do x-channels, 2,3 do h-channels). Grid 256 = 1 block/CU minimum capacity
// at __launch_bounds__(512,2) -> all blocks resident by construction, no
// cooperative launch needed (coop launch no-ops under graph capture).
// Cross-block h dependency (neighbor row-pair at t-1) via per-pair flags:
//   producer: __syncthreads (drains stores) -> __threadfence_system (L2
//   writeback) -> SYSTEM-scope release store flag=t+1.
//   consumer: SYSTEM-scope acquire spin (bypasses L1/L2, reads coherence
//   point). All h addresses are fresh per t, so no stale-cache path exists
//   regardless of block->XCD placement.
// c state lives in registers for the whole sequence.
__global__ __launch_bounds__(512, 2) void lstm_kernel(
    const float* __restrict__ x, const float* __restrict__ dwpk,
    const _Float16* __restrict__ wB, const float* __restrict__ bn2,
    float* __restrict__ out, int* __restrict__ flags)
{
    // Two A tiles (one per row of the pair): [64 s][128 cc] f16, pitch 136
    __shared__ _Float16 Alds[2][64 * 136];

    int tid = threadIdx.x;
    // XCD swizzle (perf heuristic only): batch = bid&7 so each batch's
    // h rows / x_t concentrate in one XCD's L2.
    int bid = blockIdx.x;
    int mapped = (bid & 7) * 32 + (bid >> 3);
    int ypair = mapped & 31;
    int b = mapped >> 5;

    int w = tid >> 6;
    int lane = tid & 63;
    int rh = w >> 2;                 // row half: 0 -> row 2y, 1 -> row 2y+1
    int wq = w & 3;                  // role within the half (as 4-wave kernel)
    int y0 = (ypair << 1) + rh;
    int s0 = y0 << 6;
    int col = lane & 15, quad = lane >> 4;
    int hc = wq * 16 + col;
    bool hwave = (wq >= 2);

    // ---- once: weight (B) fragments, BN2 consts ----
    half8 bfr[4][4];   // [nt gate][kc]
    #pragma unroll
    for (int nt = 0; nt < 4; ++nt)
        #pragma unroll
        for (int kc = 0; kc < 4; ++kc)
            bfr[nt][kc] = *(const half8*)(wB + (size_t)((nt << 6) + hc) * 128 + kc * 32 + quad * 8);

    float sc[4], sh[4];
    #pragma unroll
    for (int nt = 0; nt < 4; ++nt) {
        sc[nt] = bn2[(nt << 6) + hc];
        sh[nt] = bn2[256 + (nt << 6) + hc];
    }

    // ---- c state in registers for the whole sequence ----
    float creg[4][4];
    #pragma unroll
    for (int mt = 0; mt < 4; ++mt)
        #pragma unroll
        for (int r = 0; r < 4; ++r) creg[mt][r] = 0.f;

    int* myflags = flags + (b << 5);
    _Float16* A = Alds[rh];

    for (int t = 0; t < 20; ++t) {
        // ---- depthwise phase ----
        if (!hwave) {
            const float* src0 = x + ((((size_t)(b * 20 + t)) * 64 + (wq << 5)) << 12);
            dw_rows(src0, dwpk, wq << 5, y0, lane, A);
        } else if (t == 0) {
            // h == 0: conv output is 0, z = BN1 shift only
            #pragma unroll
            for (int it = 0; it < 16; ++it) {
                int cc = (wq << 5) + (it << 1);
                float sha = dwpk[cc * 12 + 10];
                float shb = dwpk[cc * 12 + 22];
                A[lane * 136 + cc]     = (_Float16)selu_f(sha);
                A[lane * 136 + cc + 1] = (_Float16)selu_f(shb);
            }
        } else {
            // rh=0 reads rows 2y-1..2y+1 -> needs pair y-1 done with t-1;
            // rh=1 reads rows 2y..2y+2   -> needs pair y+1 done with t-1;
            // own rows are ready by program order.
            int nb = (rh == 0) ? (ypair - 1) : (ypair + 1);
            if (nb >= 0 && nb < 32) {
                while (__hip_atomic_load(&myflags[nb], __ATOMIC_ACQUIRE,
                                         __HIP_MEMORY_SCOPE_SYSTEM) < t)
                    __builtin_amdgcn_s_sleep(2);
            }
            const float* src0 = out + ((((size_t)(b * 20 + (t - 1))) * 64 + ((wq - 2) << 5)) << 12);
            dw_rows(src0, dwpk, wq << 5, y0, lane, A);
        }

        __syncthreads();

        // ---- MFMA main: 4 kc x (4 mt A-frags from LDS, 16 mfmas) ----
        float4v acc[4][4];
        #pragma unroll
        for (int mt = 0; mt < 4; ++mt)
            #pragma unroll
            for (int nt = 0; nt < 4; ++nt)
                acc[mt][nt] = (float4v){0.f, 0.f, 0.f, 0.f};

        #pragma unroll
        for (int kc = 0; kc < 4; ++kc) {
            half8 a[4];
            #pragma unroll
            for (int mt = 0; mt < 4; ++mt)
                a[mt] = *(const half8*)(A + (mt * 16 + col) * 136 + kc * 32 + quad * 8);
            #pragma unroll
            for (int mt = 0; mt < 4; ++mt)
                #pragma unroll
                for (int nt = 0; nt < 4; ++nt)
                    acc[mt][nt] = __builtin_amdgcn_mfma_f32_16x16x32_f16(a[mt], bfr[nt][kc], acc[mt][nt], 0, 0, 0);
        }

        // ---- epilogue: BN2+SELU+sigmoid per gate, LSTM update (c in regs) ----
        size_t obase = (((size_t)((b * 20 + t) * 64 + hc)) << 12) + s0;
        #pragma unroll
        for (int mt = 0; mt < 4; ++mt) {
            #pragma unroll
            for (int r = 0; r < 4; ++r) {
                int sl = mt * 16 + quad * 4 + r;
                float gi = gate_f(acc[mt][0][r], sc[0], sh[0]);
                float gf = gate_f(acc[mt][1][r], sc[1], sh[1]);
                float go = gate_f(acc[mt][2][r], sc[2], sh[2]);
                float gg = gate_f(acc[mt][3][r], sc[3], sh[3]);
                float cn = gf * creg[mt][r] + gi * gg;
                creg[mt][r] = cn;
                // tanh via exp: tanh(x) = 1 - 2/(exp(2x)+1)
                float th = 1.f - 2.f / (__expf(2.f * cn) + 1.f);
                out[obase + sl] = go * th;
            }
        }

        // all waves' out-writes drained (vmcnt(0) before barrier), all Alds
        // reads done
        __syncthreads();
        if (tid == 0) {
            __threadfence_system();   // write back dirty L2 -> device-visible
            __hip_atomic_store(&myflags[ypair], t + 1, __ATOMIC_RELEASE,
                               __HIP_MEMORY_SCOPE_SYSTEM);
        }
    }
}

extern "C" void kernel_launch(void* const* d_in, const int* in_sizes, int n_in,
                              void* d_out, int out_size, void* d_ws, size_t ws_size,
                              hipStream_t stream) {
    const float* x    = (const float*)d_in[0];
    const float* dw_w = (const float*)d_in[1];
    const float* g1   = (const float*)d_in[2];
    const float* b1   = (const float*)d_in[3];
    const float* m1   = (const float*)d_in[4];
    const float* v1   = (const float*)d_in[5];
    const float* pw_w = (const float*)d_in[6];
    const float* g2   = (const float*)d_in[7];
    const float* b2   = (const float*)d_in[8];
    const float* m2   = (const float*)d_in[9];
    const float* v2   = (const float*)d_in[10];
    float* out = (float*)d_out;

    // ws layout (floats): wB16 [32768 halves = 16384 f] | bn2 [512 f] |
    //                     dwpk [1536 f] | flags [256 int]
    _Float16* wB16 = (_Float16*)d_ws;
    float* bn2  = (float*)d_ws + 16384;
    float* dwpk = bn2 + 512;
    int* flags  = (int*)(dwpk + 1536);

    prep_kernel<<<136, 256, 0, stream>>>(pw_w, g1, b1, m1, v1,
                                         g2, b2, m2, v2, dw_w,
                                         wB16, bn2, dwpk, flags);

    lstm_kernel<<<256, 512, 0, stream>>>(x, dwpk, wB16, bn2, out, flags);
}

// Round 6
// 875.518 us; speedup vs baseline: 1.3033x; 1.3033x over previous
//
#include <hip/hip_runtime.h>
#include <math.h>

typedef _Float16 half8 __attribute__((ext_vector_type(8)));
typedef float float4v __attribute__((ext_vector_type(4)));

#define SELU_ALPHA 1.6732632423543772f
#define SELU_SCALE 1.0507009873554805f

__device__ __forceinline__ float selu_f(float x) {
    return x > 0.f ? SELU_SCALE * x : SELU_SCALE * SELU_ALPHA * (__expf(x) - 1.f);
}
__device__ __forceinline__ float gate_f(float a, float sc, float sh) {
    // BN (pre-folded) -> SELU -> sigmoid
    float z = a * sc + sh;
    float s = selu_f(z);
    return 1.f / (1.f + __expf(-s));
}

// depthwise 3x3 for TWO adjacent channels at one row of 64 px (lane = px).
// 3x3 factored into column sums P/Q/R so the x-taps cost 2 shuffles/ch.
// Returns BN1-applied pre-SELU values za, zb.
__device__ __forceinline__ void dw2(
    const float* __restrict__ chA, const float* __restrict__ chB,
    const float* __restrict__ wbase, int y0, int p, int lane,
    float& za, float& zb)
{
    float a0 = (y0 > 0)  ? chA[p - 64] : 0.f;
    float a1 = chA[p];
    float a2 = (y0 < 63) ? chA[p + 64] : 0.f;
    float c0 = (y0 > 0)  ? chB[p - 64] : 0.f;
    float c1 = chB[p];
    float c2 = (y0 < 63) ? chB[p + 64] : 0.f;
    const float4v* wp = (const float4v*)wbase;
    float4v wa0 = wp[0], wa1 = wp[1], wa2 = wp[2];   // ch A: w00..w22, sc, sh
    float4v wb0 = wp[3], wb1 = wp[4], wb2 = wp[5];   // ch B
    float P  = fmaf(wa0[0], a0, fmaf(wa0[3], a1, wa1[2] * a2));
    float Q  = fmaf(wa0[1], a0, fmaf(wa1[0], a1, wa1[3] * a2));
    float R  = fmaf(wa0[2], a0, fmaf(wa1[1], a1, wa2[0] * a2));
    float P2 = fmaf(wb0[0], c0, fmaf(wb0[3], c1, wb1[2] * c2));
    float Q2 = fmaf(wb0[1], c0, fmaf(wb1[0], c1, wb1[3] * c2));
    float R2 = fmaf(wb0[2], c0, fmaf(wb1[1], c1, wb2[0] * c2));
    float Pl  = __shfl_up(P, 1);    if (lane == 0)  Pl  = 0.f;
    float Rr  = __shfl_down(R, 1);  if (lane == 63) Rr  = 0.f;
    float P2l = __shfl_up(P2, 1);   if (lane == 0)  P2l = 0.f;
    float R2r = __shfl_down(R2, 1); if (lane == 63) R2r = 0.f;
    za = fmaf(Pl + Q + Rr,    wa2[1], wa2[2]);
    zb = fmaf(P2l + Q2 + R2r, wb2[1], wb2[2]);
}

// One-time prep:
//  - cast pw_w to f16 (layout [c4][cc], MFMA-B friendly)
//  - fold BN2 into scale/shift
//  - pack per-channel dw data: 9 weights + BN1 scale + BN1 shift + pad = 12 f
// threads: 32768 (wB) + 256 (bn2) + 1536 (dwpk) = 34560 = 135*256
__global__ __launch_bounds__(256) void prep_kernel(
    const float* __restrict__ pw_w,
    const float* __restrict__ g1, const float* __restrict__ b1,
    const float* __restrict__ m1, const float* __restrict__ v1,
    const float* __restrict__ g2, const float* __restrict__ b2,
    const float* __restrict__ m2, const float* __restrict__ v2,
    const float* __restrict__ dw_w,
    _Float16* __restrict__ wB, float* __restrict__ bn2, float* __restrict__ dwpk)
{
    int i = blockIdx.x * 256 + threadIdx.x;
    if (i < 32768) {
        wB[i] = (_Float16)pw_w[i];
    } else if (i < 32768 + 256) {
        int c = i - 32768;
        float sc = g2[c] * rsqrtf(v2[c] + 1e-5f);
        bn2[c] = sc;
        bn2[256 + c] = b2[c] - m2[c] * sc;
    } else if (i < 32768 + 256 + 1536) {
        int j = i - 33024;
        int c = j / 12, k = j - c * 12;
        float val;
        if (k < 9) {
            val = dw_w[c * 9 + k];
        } else {
            float sc = g1[c] * rsqrtf(v1[c] + 1e-5f);
            if (k == 9) val = sc;
            else if (k == 10) val = b1[c] - m1[c] * sc;
            else val = 0.f;
        }
        dwpk[c * 12 + k] = val;
    }
}

// Precompute the t-independent x-half of the depthwise stage for ALL 20
// timesteps: z1x[b][t][y][px][cc0..64) f16 = selu(bn1(dw3x3(x))).
// Block = (y, t, b); 4 waves x 16 channels; lane = px. Results accumulate in
// registers (half8 x2 per lane) and are written coalesced-contiguous per lane.
// 10240 blocks -> fully occupancy/BW-bound, off the serial critical path.
__global__ __launch_bounds__(256) void zx_kernel(
    const float* __restrict__ x, const float* __restrict__ dwpk,
    _Float16* __restrict__ z1x)
{
    int tid = threadIdx.x;
    int y0 = blockIdx.x, t = blockIdx.y, b = blockIdx.z;
    int w = tid >> 6, lane = tid & 63;
    const float* src0 = x + (((size_t)(b * 20 + t) * 64 + (w << 4)) << 12);
    int p = (y0 << 6) + lane;
    half8 r[2];
    #pragma unroll
    for (int it = 0; it < 8; ++it) {
        int cl = it << 1;                  // 0,2,..,14
        int cc = (w << 4) + cl;            // x channel, < 64
        const float* chA = src0 + ((size_t)cl << 12);
        const float* chB = chA + 4096;
        float za, zb;
        dw2(chA, chB, dwpk + cc * 12, y0, p, lane, za, zb);
        r[cl >> 3][cl & 7]       = (_Float16)selu_f(za);
        r[cl >> 3][(cl & 7) + 1] = (_Float16)selu_f(zb);
    }
    size_t o = ((((size_t)(b * 20 + t) * 64 + y0) * 64 + lane) << 6) + (w << 4);
    *(half8*)(z1x + o)     = r[0];
    *(half8*)(z1x + o + 8) = r[1];
}

// Fused ConvLSTM cell for one timestep (launched 20x; launch boundary gives
// correct h coherence for free). Block = one y-row x one batch, 512 threads
// = 8 waves; __launch_bounds__(512,4) caps VGPR at 128 -> 2 blocks/CU = 16
// waves/CU (2x the latency hiding of the 4-wave version).
// Phase 1: stage precomputed z1x tile (8KB memcpy) + depthwise for the 64
//   h-channels only (8 ch/wave = 12 loads/lane, was 96).
// Phase 2: MFMA GEMM M=64,N=256,K=128 split across wave pairs on M
//   (rhalf = w>>2 owns rows rhalf*32..+32), + BN2/SELU/sigmoid/LSTM epilogue.
__global__ __launch_bounds__(512, 4) void cell_kernel(
    const _Float16* __restrict__ z1x, const float* __restrict__ hsrc,
    const float* __restrict__ dwpk, const _Float16* __restrict__ wB,
    const float* __restrict__ bn2,
    float* __restrict__ cbuf, float* __restrict__ out, int t)
{
    // A tile: [64 px][128 cc] f16, pitch 136 halves (272B rows: 16B-aligned
    // for ds_read_b128, breaks the power-of-2 bank stride)
    __shared__ _Float16 A[64 * 136];

    int tid = threadIdx.x;
    // XCD swizzle (perf heuristic): xcd = bid&7 = batch -> each batch's h,
    // cbuf, z1x slice concentrates in one XCD's L2/IC path.
    int bid = blockIdx.x;
    int mapped = (bid & 7) * 64 + (bid >> 3);
    int y0 = mapped & 63;
    int b = mapped >> 6;
    int s0 = y0 << 6;

    int w = tid >> 6, lane = tid & 63;
    int col = lane & 15, quad = lane >> 4;
    int rhalf = w >> 2;              // M half: rows rhalf*32 .. +32
    int wq = w & 3;                  // gate-column group
    int hc = (wq << 4) + col;

    // ---- weight (B) fragments + BN2 consts (L2/IC-hot after 1st launch) ----
    half8 bfr[4][4];   // [nt gate][kc]
    #pragma unroll
    for (int nt = 0; nt < 4; ++nt)
        #pragma unroll
        for (int kc = 0; kc < 4; ++kc)
            bfr[nt][kc] = *(const half8*)(wB + (size_t)((nt << 6) + hc) * 128 + kc * 32 + quad * 8);

    float sc[4], sh[4];
    #pragma unroll
    for (int nt = 0; nt < 4; ++nt) {
        sc[nt] = bn2[(nt << 6) + hc];
        sh[nt] = bn2[256 + (nt << 6) + hc];
    }

    // ---- phase 1a: stage x-half of A from precomputed z1x (8KB) ----
    {
        int px = tid >> 3, part = tid & 7;
        const half8 v = *(const half8*)(z1x +
            ((((size_t)(b * 20 + t) * 64 + y0) * 64 + px) << 6) + (part << 3));
        *(half8*)(A + px * 136 + (part << 3)) = v;
    }

    // ---- phase 1b: h-half depthwise (8 channels per wave) ----
    if (t == 0) {
        // h == 0: conv output is 0, z = BN1 shift only
        #pragma unroll
        for (int it = 0; it < 4; ++it) {
            int cc = 64 + (w << 3) + (it << 1);
            A[lane * 136 + cc]     = (_Float16)selu_f(dwpk[cc * 12 + 10]);
            A[lane * 136 + cc + 1] = (_Float16)selu_f(dwpk[cc * 12 + 22]);
        }
    } else {
        const float* src0 = hsrc + (((size_t)(b * 20 + (t - 1)) * 64 + (w << 3)) << 12);
        int p = s0 + lane;
        #pragma unroll
        for (int it = 0; it < 4; ++it) {
            int cl = it << 1;
            int cc = 64 + (w << 3) + cl;
            const float* chA = src0 + ((size_t)cl << 12);
            const float* chB = chA + 4096;
            float za, zb;
            dw2(chA, chB, dwpk + cc * 12, y0, p, lane, za, zb);
            A[lane * 136 + cc]     = (_Float16)selu_f(za);
            A[lane * 136 + cc + 1] = (_Float16)selu_f(zb);
        }
    }

    __syncthreads();

    // ---- MFMA main: 4 kc x (2 mt A-frags from LDS, 8 mfmas) ----
    float4v acc[2][4];
    #pragma unroll
    for (int mt = 0; mt < 2; ++mt)
        #pragma unroll
        for (int nt = 0; nt < 4; ++nt)
            acc[mt][nt] = (float4v){0.f, 0.f, 0.f, 0.f};

    #pragma unroll
    for (int kc = 0; kc < 4; ++kc) {
        half8 a[2];
        #pragma unroll
        for (int mt = 0; mt < 2; ++mt)
            a[mt] = *(const half8*)(A + ((rhalf << 5) + (mt << 4) + col) * 136
                                      + (kc << 5) + (quad << 3));
        #pragma unroll
        for (int mt = 0; mt < 2; ++mt)
            #pragma unroll
            for (int nt = 0; nt < 4; ++nt)
                acc[mt][nt] = __builtin_amdgcn_mfma_f32_16x16x32_f16(
                    a[mt], bfr[nt][kc], acc[mt][nt], 0, 0, 0);
    }

    // ---- epilogue: BN2+SELU+sigmoid per gate, LSTM update ----
    size_t cbase = (((size_t)(b * 64 + hc)) << 12) + s0;
    size_t obase = (((size_t)((b * 20 + t) * 64 + hc)) << 12) + s0;

    #pragma unroll
    for (int mt = 0; mt < 2; ++mt) {
        #pragma unroll
        for (int r = 0; r < 4; ++r) {
            int sl = (rhalf << 5) + (mt << 4) + (quad << 2) + r;
            float gi = gate_f(acc[mt][0][r], sc[0], sh[0]);
            float gf = gate_f(acc[mt][1][r], sc[1], sh[1]);
            float go = gate_f(acc[mt][2][r], sc[2], sh[2]);
            float gg = gate_f(acc[mt][3][r], sc[3], sh[3]);
            float cp = (t == 0) ? 0.f : cbuf[cbase + sl];
            float cn = gf * cp + gi * gg;
            cbuf[cbase + sl] = cn;
            // tanh via exp: tanh(x) = 1 - 2/(exp(2x)+1)
            float th = 1.f - 2.f / (__expf(2.f * cn) + 1.f);
            out[obase + sl] = go * th;
        }
    }
}

extern "C" void kernel_launch(void* const* d_in, const int* in_sizes, int n_in,
                              void* d_out, int out_size, void* d_ws, size_t ws_size,
                              hipStream_t stream) {
    const float* x    = (const float*)d_in[0];
    const float* dw_w = (const float*)d_in[1];
    const float* g1   = (const float*)d_in[2];
    const float* b1   = (const float*)d_in[3];
    const float* m1   = (const float*)d_in[4];
    const float* v1   = (const float*)d_in[5];
    const float* pw_w = (const float*)d_in[6];
    const float* g2   = (const float*)d_in[7];
    const float* b2   = (const float*)d_in[8];
    const float* m2   = (const float*)d_in[9];
    const float* v2   = (const float*)d_in[10];
    float* out = (float*)d_out;

    // ws layout (floats): wB16 [32768 halves = 16384 f] | bn2 [512 f] |
    //   dwpk [1536 f] | cbuf [8*64*4096 f = 8MB] | z1x [8*20*64*4096 halves = 84MB]
    _Float16* wB16 = (_Float16*)d_ws;
    float* bn2  = (float*)d_ws + 16384;
    float* dwpk = bn2 + 512;
    float* cbuf = dwpk + 1536;
    _Float16* z1x = (_Float16*)(cbuf + (size_t)8 * 64 * 4096);

    prep_kernel<<<135, 256, 0, stream>>>(pw_w, g1, b1, m1, v1,
                                         g2, b2, m2, v2, dw_w,
                                         wB16, bn2, dwpk);

    zx_kernel<<<dim3(64, 20, 8), 256, 0, stream>>>(x, dwpk, z1x);

    for (int t = 0; t < 20; ++t) {
        cell_kernel<<<512, 512, 0, stream>>>(z1x, out, dwpk, wB16, bn2,
                                             cbuf, out, t);
    }
}